// Round 4
// baseline (170.398 us; speedup 1.0000x reference)
//
#include <hip/hip_runtime.h>

// Problem constants (fixed by setup_inputs)
#define B_     8
#define C_     512
#define L_     4096
#define WC_    64
#define KS_    7
#define G_     8          // C_/WC_ channels per w row
#define TILE_  1024
#define NT_    4          // L_/TILE_

// Counted vmcnt wait with compile-time immediate.
template<int N>
__device__ __forceinline__ void waitvm() {
    asm volatile("s_waitcnt vmcnt(%0)" :: "n"(N) : "memory");
}

__device__ __forceinline__ void gload_lds16(const float* src, float* dst) {
    // 16B per lane, dest = wave-uniform base + lane*16
    __builtin_amdgcn_global_load_lds(
        (const __attribute__((address_space(1))) void*)src,
        (__attribute__((address_space(3))) void*)dst, 16, 0, 0);
}

// One L-tile of 1024 cols for one (b,wc): all 8 channels.
// Wave wv owns cols [wv*256, wv*256+256) of the tile; it stages exactly that
// region of w into LDS and consumes only it -> NO barriers anywhere.
// vmcnt queue per wave (in-order): [S_cur(7)][prev stores][X(24)][S_next(7)][stores...]
//   PRE_WAIT retires S_cur before the w ds_reads.
//   Per-channel waits (HAS_NEXT?28:21)-2g retire X_g without touching S_next.
template<bool HAS_NEXT, int PRE_WAIT>
__device__ __forceinline__ void do_tile(const float* __restrict__ xbase,
                                        float* __restrict__ obase,
                                        const float* __restrict__ wg,
                                        float (*wlds)[KS_][TILE_],
                                        int buf, int tile,
                                        int wvc, int lane) {
    const int l0 = tile * TILE_ + wvc + lane * 4;
    const int lo_off = (l0 == 0)       ? l0 : l0 - 4;
    const int hi_off = (l0 == L_ - 4)  ? l0 : l0 + 4;

    // ---- X block: 24 global float4 loads, all issued first ----
    float4 lo[G_], md[G_], hi[G_];
    #pragma unroll
    for (int g = 0; g < G_; ++g) {
        const float* xr = xbase + (size_t)g * L_;
        lo[g] = *reinterpret_cast<const float4*>(xr + lo_off);
        md[g] = *reinterpret_cast<const float4*>(xr + l0);
        hi[g] = *reinterpret_cast<const float4*>(xr + hi_off);
    }
    asm volatile("" ::: "memory");   // pin: X before S_next

    // ---- stage next tile's w (7 DMA ops, zero VGPR) ----
    if (HAS_NEXT) {
        #pragma unroll
        for (int k = 0; k < KS_; ++k)
            gload_lds16(wg + (size_t)k * L_ + (tile + 1) * TILE_ + wvc + lane * 4,
                        &wlds[buf ^ 1][k][wvc]);
    }
    asm volatile("" ::: "memory");

    waitvm<PRE_WAIT>();              // S_cur retired -> LDS buf valid

    // ---- w fragment from LDS (7 ds_read_b128, reused by all 8 channels) ----
    float4 wf[KS_];
    #pragma unroll
    for (int k = 0; k < KS_; ++k)
        wf[k] = *reinterpret_cast<const float4*>(&wlds[buf][k][wvc + lane * 4]);

    const bool lo_z = (l0 == 0);
    const bool hi_z = (l0 == L_ - 4);
    const float4 z4 = make_float4(0.f, 0.f, 0.f, 0.f);

    // out[l0+j] = sum_k xe[j+k+1] * wf[k][j],  xe[i] = x[l0-4+i]
    #define CHAN(gi)                                                          \
    {                                                                         \
        waitvm<(HAS_NEXT ? 28 : 21) - 2 * gi>();                              \
        float4 Lq = lo[gi]; if (lo_z) Lq = z4;                                \
        float4 Mq = md[gi];                                                   \
        float4 Hq = hi[gi]; if (hi_z) Hq = z4;                                \
        const float xe1 = Lq.y, xe2 = Lq.z, xe3 = Lq.w;                       \
        const float xe4 = Mq.x, xe5 = Mq.y, xe6 = Mq.z, xe7 = Mq.w;           \
        const float xe8 = Hq.x, xe9 = Hq.y, xe10 = Hq.z;                      \
        float ax = xe1 * wf[0].x, ay = xe2 * wf[0].y,                         \
              az = xe3 * wf[0].z, aw = xe4 * wf[0].w;                         \
        ax = fmaf(xe2, wf[1].x, ax); ay = fmaf(xe3, wf[1].y, ay);             \
        az = fmaf(xe4, wf[1].z, az); aw = fmaf(xe5, wf[1].w, aw);             \
        ax = fmaf(xe3, wf[2].x, ax); ay = fmaf(xe4, wf[2].y, ay);             \
        az = fmaf(xe5, wf[2].z, az); aw = fmaf(xe6, wf[2].w, aw);             \
        ax = fmaf(xe4, wf[3].x, ax); ay = fmaf(xe5, wf[3].y, ay);             \
        az = fmaf(xe6, wf[3].z, az); aw = fmaf(xe7, wf[3].w, aw);             \
        ax = fmaf(xe5, wf[4].x, ax); ay = fmaf(xe6, wf[4].y, ay);             \
        az = fmaf(xe7, wf[4].z, az); aw = fmaf(xe8, wf[4].w, aw);             \
        ax = fmaf(xe6, wf[5].x, ax); ay = fmaf(xe7, wf[5].y, ay);             \
        az = fmaf(xe8, wf[5].z, az); aw = fmaf(xe9, wf[5].w, aw);             \
        ax = fmaf(xe7, wf[6].x, ax); ay = fmaf(xe8, wf[6].y, ay);             \
        az = fmaf(xe9, wf[6].z, az); aw = fmaf(xe10, wf[6].w, aw);            \
        *reinterpret_cast<float4*>(obase + (size_t)gi * L_ + l0) =            \
            make_float4(ax, ay, az, aw);                                      \
        asm volatile("" ::: "memory");                                        \
    }
    CHAN(0) CHAN(1) CHAN(2) CHAN(3) CHAN(4) CHAN(5) CHAN(6) CHAN(7)
    #undef CHAN
}

__global__ __launch_bounds__(256, 2)
void SKA_40106404610132_kernel(const float* __restrict__ x,
                               const float* __restrict__ w,
                               float* __restrict__ out) {
    __shared__ float wlds[2][KS_][TILE_];   // 56 KB double-buffered w tile

    const int bid  = blockIdx.x;            // 512 blocks = B_*WC_
    const int wc   = bid & (WC_ - 1);
    const int b    = bid >> 6;
    const int tid  = threadIdx.x;
    const int wv   = tid >> 6;
    const int lane = tid & 63;
    const int wvc  = wv << 8;               // wave's 256-col region

    const float* xbase = x   + (size_t)(b * C_ + wc * G_) * L_;
    float*       obase = out + (size_t)(b * C_ + wc * G_) * L_;
    const float* wg    = w   + (size_t)(b * WC_ + wc) * KS_ * L_;

    // prologue: stage tile 0 into buf 0
    #pragma unroll
    for (int k = 0; k < KS_; ++k)
        gload_lds16(wg + (size_t)k * L_ + wvc + lane * 4, &wlds[0][k][wvc]);
    asm volatile("" ::: "memory");

    // vmcnt arithmetic (in-order retire):
    // t0: entry [S0(7)]            -> PRE = 24 + 7      = 31
    // t1: entry [S1(7)][st(8)]     -> PRE = 8 + 24 + 7  = 39
    // t2: entry [S2(7)][st(8)]     -> PRE = 39
    // t3: entry [S3(7)][st(8)], no S_next -> PRE = 8+24 = 32
    do_tile<true,  31>(xbase, obase, wg, wlds, 0, 0, wvc, lane);
    do_tile<true,  39>(xbase, obase, wg, wlds, 1, 1, wvc, lane);
    do_tile<true,  39>(xbase, obase, wg, wlds, 0, 2, wvc, lane);
    do_tile<false, 32>(xbase, obase, wg, wlds, 1, 3, wvc, lane);
}

extern "C" void kernel_launch(void* const* d_in, const int* in_sizes, int n_in,
                              void* d_out, int out_size, void* d_ws, size_t ws_size,
                              hipStream_t stream) {
    const float* x = (const float*)d_in[0];
    const float* w = (const float*)d_in[1];
    float* out = (float*)d_out;

    SKA_40106404610132_kernel<<<B_ * WC_, 256, 0, stream>>>(x, w, out);
}

// Round 5
// 164.444 us; speedup vs baseline: 1.0362x; 1.0362x over previous
//
#include <hip/hip_runtime.h>

// Problem constants (fixed by setup_inputs)
#define B_     8
#define C_     512
#define L_     4096
#define WC_    64
#define KS_    7
#define G_     8          // C_/WC_ channels per w group
#define TILE_  1024
#define NT_    4          // L_/TILE_
#define XSTR_  1032       // x LDS row stride: 1024 + 8 halo (stride%32=8 -> bank rotate)

// Canonical single-fetch form: one block per (b, wc, l-tile).
//  stage:   x tile (8 rows x 1024 + 4/4 halo, zero-padded at seq edges) -> LDS
//           w tile (7 x 1024) -> LDS            [every global byte read ONCE]
//  compute: per thread, 4 cols x 8 channels; w frag (7xfloat4) from LDS into
//           regs once; per channel 3 aligned contiguous ds_read_b128 + 28 FMA
//           + 1 float4 store. Zero branches in compute (pad handled in stage).
__global__ __launch_bounds__(256, 2)
void SKA_40106404610132_kernel(const float* __restrict__ x,
                               const float* __restrict__ w,
                               float* __restrict__ out) {
    __shared__ float xs[G_][XSTR_];     // 33.0 KB
    __shared__ float ws_[KS_][TILE_];   // 28.7 KB   (total 61.7 KB -> 2 blk/CU)

    const int bid  = blockIdx.x;                 // 2048 = 8*64*4
    const int tile = bid & (NT_ - 1);
    const int wc   = (bid >> 2) & (WC_ - 1);
    const int b    = bid >> 8;
    const int t    = threadIdx.x;

    const size_t grp = (size_t)(b * C_ + wc * G_) * L_;
    const float* xg  = x + grp + tile * TILE_;
    const float* wg  = w + ((size_t)(b * WC_ + wc) * KS_) * L_ + tile * TILE_;

    // ---- stage x main body: thread t -> row r = t>>5, 8 float4 chunks ----
    {
        const int r  = t >> 5;
        const int c4 = (t & 31) * 4;
        const float* xr = xg + (size_t)r * L_;
        float* xsr = &xs[r][4];
        #pragma unroll
        for (int i = 0; i < 8; ++i) {
            const int col = c4 + i * 128;
            *reinterpret_cast<float4*>(xsr + col) =
                *reinterpret_cast<const float4*>(xr + col);
        }
    }
    // ---- stage halos (zero at sequence edges) ----
    if (t < 8) {                         // front halo of row t
        const float4 z4 = make_float4(0.f, 0.f, 0.f, 0.f);
        *reinterpret_cast<float4*>(&xs[t][0]) =
            (tile > 0) ? *reinterpret_cast<const float4*>(xg + (size_t)t * L_ - 4)
                       : z4;
    } else if (t < 16) {                 // back halo of row t-8
        const int r = t - 8;
        const float4 z4 = make_float4(0.f, 0.f, 0.f, 0.f);
        *reinterpret_cast<float4*>(&xs[r][4 + TILE_]) =
            (tile < NT_ - 1)
                ? *reinterpret_cast<const float4*>(xg + (size_t)r * L_ + TILE_)
                : z4;
    }
    // ---- stage w: 7 rows x 256 float4, thread t covers col t of each row ----
    {
        const int c4 = t * 4;
        #pragma unroll
        for (int k = 0; k < KS_; ++k)
            *reinterpret_cast<float4*>(&ws_[k][c4]) =
                *reinterpret_cast<const float4*>(wg + (size_t)k * L_ + c4);
    }

    __syncthreads();

    // ---- compute: zero branches ----
    const int c4 = t * 4;                        // thread's 4 cols in tile
    float4 wf[KS_];
    #pragma unroll
    for (int k = 0; k < KS_; ++k)
        wf[k] = *reinterpret_cast<const float4*>(&ws_[k][c4]);

    float* og = out + grp + tile * TILE_;

    #pragma unroll
    for (int g = 0; g < G_; ++g) {
        const float* base = &xs[g][c4];          // = x[l0-4], 16B aligned
        const float4 lo = *reinterpret_cast<const float4*>(base);
        const float4 md = *reinterpret_cast<const float4*>(base + 4);
        const float4 hi = *reinterpret_cast<const float4*>(base + 8);

        const float xe1 = lo.y, xe2 = lo.z, xe3 = lo.w;
        const float xe4 = md.x, xe5 = md.y, xe6 = md.z, xe7 = md.w;
        const float xe8 = hi.x, xe9 = hi.y, xe10 = hi.z;

        float ax = xe1 * wf[0].x, ay = xe2 * wf[0].y,
              az = xe3 * wf[0].z, aw = xe4 * wf[0].w;
        ax = fmaf(xe2, wf[1].x, ax); ay = fmaf(xe3, wf[1].y, ay);
        az = fmaf(xe4, wf[1].z, az); aw = fmaf(xe5, wf[1].w, aw);
        ax = fmaf(xe3, wf[2].x, ax); ay = fmaf(xe4, wf[2].y, ay);
        az = fmaf(xe5, wf[2].z, az); aw = fmaf(xe6, wf[2].w, aw);
        ax = fmaf(xe4, wf[3].x, ax); ay = fmaf(xe5, wf[3].y, ay);
        az = fmaf(xe6, wf[3].z, az); aw = fmaf(xe7, wf[3].w, aw);
        ax = fmaf(xe5, wf[4].x, ax); ay = fmaf(xe6, wf[4].y, ay);
        az = fmaf(xe7, wf[4].z, az); aw = fmaf(xe8, wf[4].w, aw);
        ax = fmaf(xe6, wf[5].x, ax); ay = fmaf(xe7, wf[5].y, ay);
        az = fmaf(xe8, wf[5].z, az); aw = fmaf(xe9, wf[5].w, aw);
        ax = fmaf(xe7, wf[6].x, ax); ay = fmaf(xe8, wf[6].y, ay);
        az = fmaf(xe9, wf[6].z, az); aw = fmaf(xe10, wf[6].w, aw);

        *reinterpret_cast<float4*>(og + (size_t)g * L_ + c4) =
            make_float4(ax, ay, az, aw);
    }
}

extern "C" void kernel_launch(void* const* d_in, const int* in_sizes, int n_in,
                              void* d_out, int out_size, void* d_ws, size_t ws_size,
                              hipStream_t stream) {
    const float* x = (const float*)d_in[0];
    const float* w = (const float*)d_in[1];
    float* out = (float*)d_out;

    SKA_40106404610132_kernel<<<B_ * WC_ * NT_, 256, 0, stream>>>(x, w, out);
}